// Round 1
// baseline (342.432 us; speedup 1.0000x reference)
//
#include <hip/hip_runtime.h>
#include <hip/hip_bf16.h>

typedef __attribute__((ext_vector_type(8))) short short8;
typedef __attribute__((ext_vector_type(4))) float f32x4;

#define LN_EPS 1e-5f
#define NT 384      // N tokens
#define SD 64       // S
#define CI 64       // c_in
#define CH 32       // c_hidden
#define CO 128      // c_out
#define ZSTRIDE 1032  // 1024 + 8 bf16 pad (16B aligned rows, breaks bank conflicts)

// ---------------- Kernel 1: LayerNorm + dual projection + mask, emit bf16 ----------------
// One wave per (s,n) row. a_out[n][c][s], b_out[n][c][s] (s contiguous) — MFMA-friendly.
__global__ __launch_bounds__(256) void ln_proj_kernel(
    const float* __restrict__ m, const int* __restrict__ mask,
    const float* __restrict__ gamma, const float* __restrict__ beta,
    const float* __restrict__ Wa, const float* __restrict__ Wb,
    __hip_bfloat16* __restrict__ a_out, __hip_bfloat16* __restrict__ b_out)
{
    __shared__ float mn_s[4][64];
    int wv = threadIdx.x >> 6, lane = threadIdx.x & 63;
    int row = blockIdx.x * 4 + wv;            // row = s*384 + n, rows = 24576
    float x = m[row * 64 + lane];
    float v = x;
    #pragma unroll
    for (int off = 1; off < 64; off <<= 1) v += __shfl_xor(v, off);
    float mu = v * (1.0f / 64.0f);
    float d = x - mu;
    float v2 = d * d;
    #pragma unroll
    for (int off = 1; off < 64; off <<= 1) v2 += __shfl_xor(v2, off);
    float rstd = rsqrtf(v2 * (1.0f / 64.0f) + LN_EPS);
    mn_s[wv][lane] = d * rstd * gamma[lane] + beta[lane];
    float mf = (float)mask[row];
    __syncthreads();

    int half = lane >> 5, c = lane & 31;
    const float* __restrict__ W = half ? Wb : Wa;
    float acc = 0.f;
    #pragma unroll
    for (int k = 0; k < 64; ++k) acc += mn_s[wv][k] * W[c * 64 + k];
    acc *= mf;
    int n = row % NT, s = row / NT;
    __hip_bfloat16* dst = half ? b_out : a_out;
    dst[(n * CH + c) * SD + s] = __float2bfloat16(acc);
}

// ---------------- Kernel 2: pairwise mask denom -> reciprocal of clip(.,1) ----------------
__global__ __launch_bounds__(384) void denom_kernel(const int* __restrict__ mask,
                                                    float* __restrict__ rdenom)
{
    int i = blockIdx.x, j = threadIdx.x;
    int acc = 0;
    #pragma unroll 8
    for (int s = 0; s < SD; ++s)
        acc += mask[s * NT + i] * mask[s * NT + j];
    rdenom[i * NT + j] = 1.0f / (float)max(acc, 1);
}

// ---------------- Kernel 3: Wo -> bf16 ----------------
__global__ __launch_bounds__(512) void wo_conv_kernel(const float* __restrict__ wo,
                                                      __hip_bfloat16* __restrict__ wo_bf)
{
    int idx = blockIdx.x * 512 + threadIdx.x;
    if (idx < CO * 1024) wo_bf[idx] = __float2bfloat16(wo[idx]);
}

// ---------------- Kernel 4: fused outer-product-mean + down-projection ----------------
// Grid: 12 j-blocks x 384 i.  Block = 512 threads (8 waves).
// Stage A: z[j][c*32+d] (32x1024 bf16 in LDS) = sum_s a[s,i,c]*b[s,j,d], scaled by rdenom.
//   GEMM M=(j,d)=1024 (64 mtiles), N=c=32 (2 ntiles), K=s=64 (2 ksteps).
// Stage B: out[j][o] = z @ Wo^T + bo.  GEMM M=j=32, N=o=128, K=1024.
__global__ __launch_bounds__(512, 4) void opm_kernel(
    const __hip_bfloat16* __restrict__ a2,   // [384][32][64]
    const __hip_bfloat16* __restrict__ bt,   // [384][32][64]
    const __hip_bfloat16* __restrict__ wo,   // [128][1024]
    const float* __restrict__ rdenom,        // [384][384]
    const float* __restrict__ bo,            // [128]
    float* __restrict__ out)                 // [384][384][128]
{
    __shared__ __hip_bfloat16 z_lds[32 * ZSTRIDE];  // 66048 B
    __shared__ __hip_bfloat16 a_lds[32 * 72];       // padded rows (64+8)
    __shared__ float rd_lds[32];

    int bid = blockIdx.x;
    int jb = bid / NT;          // 0..11  (consecutive blocks share the b-block in L2)
    int i  = bid % NT;          // 0..383
    int tid = threadIdx.x;
    int w = tid >> 6, lane = tid & 63;
    int l15 = lane & 15, quad = lane >> 4;

    // load a-row for this i into LDS (2048 bf16), 8B per thread
    {
        const ushort* __restrict__ src = (const ushort*)(a2 + i * (CH * SD));
        int c = tid >> 4;              // tid*4/64
        int s = (tid & 15) * 4;
        ushort4 val = *(const ushort4*)(src + tid * 4);
        *(ushort4*)((ushort*)a_lds + c * 72 + s) = val;
    }
    if (tid < 32) rd_lds[tid] = rdenom[i * NT + jb * 32 + tid];
    __syncthreads();

    // ---- Stage A ----
    short8 bfrag[2][2];
    #pragma unroll
    for (int nt = 0; nt < 2; ++nt)
        #pragma unroll
        for (int ks = 0; ks < 2; ++ks)
            bfrag[nt][ks] = *(const short8*)((const ushort*)a_lds +
                                (nt * 16 + l15) * 72 + ks * 32 + quad * 8);

    for (int mt = w; mt < 64; mt += 8) {
        int mrow = mt * 16 + l15;          // global M index = jl*32 + d
        int jl = mrow >> 5, dd = mrow & 31;
        const __hip_bfloat16* abase = bt + (((jb * 32 + jl) * CH + dd) * SD) + quad * 8;
        short8 af0 = *(const short8*)(abase);
        short8 af1 = *(const short8*)(abase + 32);
        f32x4 acc0 = {0.f, 0.f, 0.f, 0.f};
        f32x4 acc1 = {0.f, 0.f, 0.f, 0.f};
        acc0 = __builtin_amdgcn_mfma_f32_16x16x32_bf16(af0, bfrag[0][0], acc0, 0, 0, 0);
        acc0 = __builtin_amdgcn_mfma_f32_16x16x32_bf16(af1, bfrag[0][1], acc0, 0, 0, 0);
        acc1 = __builtin_amdgcn_mfma_f32_16x16x32_bf16(af0, bfrag[1][0], acc1, 0, 0, 0);
        acc1 = __builtin_amdgcn_mfma_f32_16x16x32_bf16(af1, bfrag[1][1], acc1, 0, 0, 0);
        #pragma unroll
        for (int r = 0; r < 4; ++r) {
            int mm = mt * 16 + quad * 4 + r;
            int jl2 = mm >> 5, d2 = mm & 31;
            float rd = rd_lds[jl2];
            z_lds[jl2 * ZSTRIDE + l15 * 32 + d2]        = __float2bfloat16(acc0[r] * rd);
            z_lds[jl2 * ZSTRIDE + (16 + l15) * 32 + d2] = __float2bfloat16(acc1[r] * rd);
        }
    }
    __syncthreads();

    // ---- Stage B ----  wave w -> ntile (o block) w; both mtiles (j 0..15, 16..31)
    int o = w * 16 + l15;
    const __hip_bfloat16* wobase = wo + o * 1024 + quad * 8;
    f32x4 acc0 = {0.f, 0.f, 0.f, 0.f};
    f32x4 acc1 = {0.f, 0.f, 0.f, 0.f};
    const ushort* zrow0 = (const ushort*)z_lds + l15 * ZSTRIDE + quad * 8;
    const ushort* zrow1 = (const ushort*)z_lds + (16 + l15) * ZSTRIDE + quad * 8;
    #pragma unroll 4
    for (int ks = 0; ks < 32; ++ks) {
        short8 wf = *(const short8*)(wobase + ks * 32);
        short8 z0 = *(const short8*)(zrow0 + ks * 32);
        short8 z1 = *(const short8*)(zrow1 + ks * 32);
        acc0 = __builtin_amdgcn_mfma_f32_16x16x32_bf16(z0, wf, acc0, 0, 0, 0);
        acc1 = __builtin_amdgcn_mfma_f32_16x16x32_bf16(z1, wf, acc1, 0, 0, 0);
    }
    float bov = bo[o];
    #pragma unroll
    for (int r = 0; r < 4; ++r) {
        int j0 = jb * 32 + quad * 4 + r;
        out[(i * NT + j0) * CO + o]        = acc0[r] + bov;
        out[(i * NT + j0 + 16) * CO + o]   = acc1[r] + bov;
    }
}

// ---------------- launch ----------------
extern "C" void kernel_launch(void* const* d_in, const int* in_sizes, int n_in,
                              void* d_out, int out_size, void* d_ws, size_t ws_size,
                              hipStream_t stream) {
    const float* m     = (const float*)d_in[0];
    const int*   mask  = (const int*)d_in[1];
    const float* gamma = (const float*)d_in[2];
    const float* beta  = (const float*)d_in[3];
    const float* Wa    = (const float*)d_in[4];
    const float* Wb    = (const float*)d_in[5];
    const float* Wo    = (const float*)d_in[6];
    const float* bo    = (const float*)d_in[7];
    float* out = (float*)d_out;

    char* ws = (char*)d_ws;
    __hip_bfloat16* a2    = (__hip_bfloat16*)(ws);                 // 384*32*64*2 = 1572864 B
    __hip_bfloat16* btp   = (__hip_bfloat16*)(ws + 1572864);       // 1572864 B
    __hip_bfloat16* wo_bf = (__hip_bfloat16*)(ws + 3145728);       // 262144 B
    float*          rden  = (float*)(ws + 3407872);                // 589824 B

    ln_proj_kernel<<<24576 / 4, 256, 0, stream>>>(m, mask, gamma, beta, Wa, Wb, a2, btp);
    wo_conv_kernel<<<(CO * 1024 + 511) / 512, 512, 0, stream>>>(Wo, wo_bf);
    denom_kernel<<<NT, NT, 0, stream>>>(mask, rden);
    opm_kernel<<<12 * NT, 512, 0, stream>>>(a2, btp, wo_bf, rden, bo, out);
}

// Round 2
// 307.917 us; speedup vs baseline: 1.1121x; 1.1121x over previous
//
#include <hip/hip_runtime.h>
#include <hip/hip_bf16.h>

typedef __attribute__((ext_vector_type(8))) short short8;
typedef __attribute__((ext_vector_type(4))) float f32x4;
typedef unsigned short u16;
typedef __attribute__((ext_vector_type(4))) u16 u16x4;
typedef __attribute__((ext_vector_type(8))) u16 u16x8;

#define LN_EPS 1e-5f
#define NT 384
#define SD 64
#define CH 32
#define CO 128

#define MFMA16(a, b, c) __builtin_amdgcn_mfma_f32_16x16x32_bf16(a, b, c, 0, 0, 0)

static __device__ __forceinline__ u16 f2bf(float v) {
    __hip_bfloat16 h = __float2bfloat16(v);
    return *reinterpret_cast<u16*>(&h);
}

// ---------------- Kernel 1: LayerNorm + dual projection + mask ----------------
// One block per n (384 blocks, 256 threads). W transposed into LDS (conflict-free),
// outputs written as coalesced 16B stores in a[n][c][s] layout.
__global__ __launch_bounds__(256) void ln_proj_kernel(
    const float* __restrict__ m, const int* __restrict__ mask,
    const float* __restrict__ gamma, const float* __restrict__ beta,
    const float* __restrict__ Wa, const float* __restrict__ Wb,
    u16* __restrict__ a_out, u16* __restrict__ b_out)
{
    __shared__ float Wl[2][64][33];   // [which][k][c], pad 33 -> bank = (k+c)%32
    __shared__ float mn_s[64][65];    // [k][s], pad 65 -> phase1 write bank = (k+s)%32
    __shared__ float mf_s[64];
    int n = blockIdx.x, tid = threadIdx.x;
    int wv = tid >> 6, lane = tid & 63;

    // stage W (coalesced global read, transposed scalar LDS writes)
    #pragma unroll
    for (int rep = 0; rep < 2; ++rep) {
        int p = rep * 1024 + tid * 4;
        int c = p >> 6, k0 = p & 63;
        float4 va = *(const float4*)(Wa + p);
        float4 vb = *(const float4*)(Wb + p);
        Wl[0][k0 + 0][c] = va.x; Wl[0][k0 + 1][c] = va.y;
        Wl[0][k0 + 2][c] = va.z; Wl[0][k0 + 3][c] = va.w;
        Wl[1][k0 + 0][c] = vb.x; Wl[1][k0 + 1][c] = vb.y;
        Wl[1][k0 + 2][c] = vb.z; Wl[1][k0 + 3][c] = vb.w;
    }

    // LayerNorm: each wave handles 16 s rows
    float gl = gamma[lane], bl = beta[lane];
    for (int it = 0; it < 16; ++it) {
        int s = wv * 16 + it;
        float x = m[(s * NT + n) * 64 + lane];
        float v = x;
        #pragma unroll
        for (int off = 1; off < 64; off <<= 1) v += __shfl_xor(v, off);
        float mu = v * (1.0f / 64.0f);
        float d = x - mu;
        float v2 = d * d;
        #pragma unroll
        for (int off = 1; off < 64; off <<= 1) v2 += __shfl_xor(v2, off);
        float rstd = rsqrtf(v2 * (1.0f / 64.0f) + LN_EPS);
        mn_s[lane][s] = d * rstd * gl + bl;
    }
    if (tid < 64) mf_s[tid] = (float)mask[tid * NT + n];
    __syncthreads();

    // projection: thread (c = tid&31, sg = tid>>5) computes a,b for 8 s values
    int c = tid & 31, sg = tid >> 5;
    float accA[8], accB[8];
    #pragma unroll
    for (int j = 0; j < 8; ++j) { accA[j] = 0.f; accB[j] = 0.f; }
    for (int k = 0; k < 64; ++k) {
        float wa = Wl[0][k][c], wb = Wl[1][k][c];
        #pragma unroll
        for (int j = 0; j < 8; ++j) {
            float mnv = mn_s[k][sg * 8 + j];
            accA[j] += mnv * wa;
            accB[j] += mnv * wb;
        }
    }
    u16x8 pa, pb;
    #pragma unroll
    for (int j = 0; j < 8; ++j) {
        float mfv = mf_s[sg * 8 + j];
        pa[j] = f2bf(accA[j] * mfv);
        pb[j] = f2bf(accB[j] * mfv);
    }
    int off = n * (CH * SD) + c * SD + sg * 8;
    *(u16x8*)(a_out + off) = pa;
    *(u16x8*)(b_out + off) = pb;
}

// ---------------- Kernel 2: pairwise mask denom -> reciprocal ----------------
__global__ __launch_bounds__(384) void denom_kernel(const int* __restrict__ mask,
                                                    float* __restrict__ rdenom)
{
    int i = blockIdx.x, j = threadIdx.x;
    int acc = 0;
    #pragma unroll 8
    for (int s = 0; s < SD; ++s)
        acc += mask[s * NT + i] * mask[s * NT + j];
    rdenom[i * NT + j] = 1.0f / (float)max(acc, 1);
}

// ---------------- Kernel 3: Wo -> bf16 ----------------
__global__ __launch_bounds__(512) void wo_conv_kernel(const float* __restrict__ wo,
                                                      u16* __restrict__ wo_bf)
{
    int idx = blockIdx.x * 512 + threadIdx.x;
    if (idx < CO * 1024) wo_bf[idx] = f2bf(wo[idx]);
}

// ---------------- Kernel 4: fused OPM + down-projection ----------------
// z stored in LDS with XOR swizzle: element (j,c,d): u=d>>3, chunk t=c*4+u,
// t' = t ^ (((j&1)<<2)|((j>>1)&3)) ^ ((c>>1)&3); byte = j*2048 + t'*16 + (d>>2&1)*8.
// Stage-A 8B writes: 4-way (b64 floor). Stage-B 16B reads: 8-way (b128 floor).
__global__ __launch_bounds__(512, 4) void opm_kernel(
    const u16* __restrict__ a2,   // [384][32][64]
    const u16* __restrict__ bt,   // [384][32][64]  (channel = d)
    const u16* __restrict__ wo,   // [128][1024]
    const float* __restrict__ rdenom,
    const float* __restrict__ bo,
    float* __restrict__ out)
{
    __shared__ u16 z_lds[32 * 1024];      // 64 KB, swizzled
    __shared__ u16 a_lds[32 * 72];        // [c][s], stride 72
    __shared__ float rd_lds[32];

    int bid = blockIdx.x;
    int jb = bid / NT;
    int i  = bid % NT;
    int tid = threadIdx.x;
    int w = tid >> 6, lane = tid & 63;
    int l15 = lane & 15, quad = lane >> 4;

    // stage a-row for this i
    {
        const u16* src = a2 + i * (CH * SD);
        int c = tid >> 4, s = (tid & 15) * 4;
        *(u16x4*)(a_lds + c * 72 + s) = *(const u16x4*)(src + tid * 4);
    }
    if (tid < 32) rd_lds[tid] = rdenom[i * NT + jb * 32 + tid];
    __syncthreads();

    // ---- Stage A: z[j][c,d] = sum_s b[j,d,s] * a[i,c,s], scaled by rdenom ----
    short8 bfrag[2][2];
    #pragma unroll
    for (int nt = 0; nt < 2; ++nt)
        #pragma unroll
        for (int ks = 0; ks < 2; ++ks)
            bfrag[nt][ks] = *(const short8*)(a_lds + (nt * 16 + l15) * 72 + ks * 32 + quad * 8);

    int uA = quad >> 1, halfA = quad & 1;
    #pragma unroll 4
    for (int it = 0; it < 8; ++it) {
        int mt = w + it * 8;
        int mrow = mt * 16 + l15;
        int jl = mrow >> 5, dd = mrow & 31;
        const u16* abase = bt + ((jb * 32 + jl) * CH + dd) * SD + quad * 8;
        short8 af0 = *(const short8*)(abase);
        short8 af1 = *(const short8*)(abase + 32);
        f32x4 acc0 = {0.f, 0.f, 0.f, 0.f};
        f32x4 acc1 = {0.f, 0.f, 0.f, 0.f};
        acc0 = MFMA16(af0, bfrag[0][0], acc0);
        acc0 = MFMA16(af1, bfrag[0][1], acc0);
        acc1 = MFMA16(af0, bfrag[1][0], acc1);
        acc1 = MFMA16(af1, bfrag[1][1], acc1);
        int j = mt >> 1;
        float rd = rd_lds[j];
        int u = (mt & 1) * 2 + uA;
        int Qj = ((j & 1) << 2) | ((j >> 1) & 3);
        int Rc = (l15 >> 1) & 3;          // same for c and c+16
        u16x4 pk0, pk1;
        #pragma unroll
        for (int r = 0; r < 4; ++r) {
            pk0[r] = f2bf(acc0[r] * rd);
            pk1[r] = f2bf(acc1[r] * rd);
        }
        int c0 = l15, c1 = 16 + l15;
        int tp0 = (c0 * 4 + u) ^ Qj ^ Rc;
        int tp1 = (c1 * 4 + u) ^ Qj ^ Rc;
        *(u16x4*)((char*)z_lds + j * 2048 + tp0 * 16 + halfA * 8) = pk0;
        *(u16x4*)((char*)z_lds + j * 2048 + tp1 * 16 + halfA * 8) = pk1;
    }
    __syncthreads();

    // ---- Stage B: out = z @ Wo^T, K-split-2 across wave pairs ----
    int np = w & 3, ksb = (w >> 2) * 16;
    const u16* wob0 = wo + (np * 32 + l15) * 1024 + quad * 8;
    const u16* wob1 = wob0 + 16 * 1024;
    int Qj = ((l15 & 1) << 2) | ((l15 >> 1) & 3);   // same for j=l15 and j=16+l15
    const char* zb0 = (const char*)z_lds + l15 * 2048;
    const char* zb1 = (const char*)z_lds + (16 + l15) * 2048;
    f32x4 acc[2][2];
    #pragma unroll
    for (int mi = 0; mi < 2; ++mi)
        #pragma unroll
        for (int nt = 0; nt < 2; ++nt)
            acc[mi][nt] = (f32x4){0.f, 0.f, 0.f, 0.f};

    #pragma unroll 4
    for (int kk = 0; kk < 16; ++kk) {
        int ks = ksb + kk;
        int tp = (ks * 4 + quad) ^ Qj ^ ((ks >> 1) & 3);
        short8 z0 = *(const short8*)(zb0 + tp * 16);
        short8 z1 = *(const short8*)(zb1 + tp * 16);
        short8 wf0 = *(const short8*)(wob0 + ks * 32);
        short8 wf1 = *(const short8*)(wob1 + ks * 32);
        acc[0][0] = MFMA16(z0, wf0, acc[0][0]);
        acc[0][1] = MFMA16(z0, wf1, acc[0][1]);
        acc[1][0] = MFMA16(z1, wf0, acc[1][0]);
        acc[1][1] = MFMA16(z1, wf1, acc[1][1]);
    }
    __syncthreads();

    // K-split reduction through LDS (z region is dead now)
    float* scratch = (float*)z_lds;
    if (w >= 4) {
        #pragma unroll
        for (int mi = 0; mi < 2; ++mi)
            #pragma unroll
            for (int nt = 0; nt < 2; ++nt)
                *(f32x4*)(scratch + (w - 4) * 1024 + (mi * 2 + nt) * 256 + lane * 4) = acc[mi][nt];
    }
    __syncthreads();
    if (w < 4) {
        float bo0 = bo[np * 32 + l15];
        float bo1 = bo[np * 32 + 16 + l15];
        #pragma unroll
        for (int mi = 0; mi < 2; ++mi) {
            #pragma unroll
            for (int nt = 0; nt < 2; ++nt) {
                f32x4 p = *(const f32x4*)(scratch + w * 1024 + (mi * 2 + nt) * 256 + lane * 4);
                f32x4 r = acc[mi][nt] + p;
                float bov = nt ? bo1 : bo0;
                int o = np * 32 + nt * 16 + l15;
                #pragma unroll
                for (int rr = 0; rr < 4; ++rr) {
                    int j = jb * 32 + mi * 16 + quad * 4 + rr;
                    out[(i * NT + j) * CO + o] = r[rr] + bov;
                }
            }
        }
    }
}

// ---------------- launch ----------------
extern "C" void kernel_launch(void* const* d_in, const int* in_sizes, int n_in,
                              void* d_out, int out_size, void* d_ws, size_t ws_size,
                              hipStream_t stream) {
    const float* m     = (const float*)d_in[0];
    const int*   mask  = (const int*)d_in[1];
    const float* gamma = (const float*)d_in[2];
    const float* beta  = (const float*)d_in[3];
    const float* Wa    = (const float*)d_in[4];
    const float* Wb    = (const float*)d_in[5];
    const float* Wo    = (const float*)d_in[6];
    const float* bo    = (const float*)d_in[7];
    float* out = (float*)d_out;

    char* ws = (char*)d_ws;
    u16*   a2    = (u16*)(ws);
    u16*   btp   = (u16*)(ws + 1572864);
    u16*   wo_bf = (u16*)(ws + 3145728);
    float* rden  = (float*)(ws + 3407872);

    ln_proj_kernel<<<NT, 256, 0, stream>>>(m, mask, gamma, beta, Wa, Wb, a2, btp);
    wo_conv_kernel<<<(CO * 1024 + 511) / 512, 512, 0, stream>>>(Wo, wo_bf);
    denom_kernel<<<NT, NT, 0, stream>>>(mask, rden);
    opm_kernel<<<12 * NT, 512, 0, stream>>>(a2, btp, wo_bf, rden, bo, out);
}

// Round 3
// 226.407 us; speedup vs baseline: 1.5125x; 1.3600x over previous
//
#include <hip/hip_runtime.h>
#include <hip/hip_bf16.h>

typedef __attribute__((ext_vector_type(8))) short short8;
typedef __attribute__((ext_vector_type(4))) float f32x4;
typedef unsigned short u16;
typedef __attribute__((ext_vector_type(4))) u16 u16x4;
typedef __attribute__((ext_vector_type(8))) u16 u16x8;

#define LN_EPS 1e-5f
#define NT 384
#define SD 64
#define CH 32
#define CO 128

#define MFMA16(a, b, c) __builtin_amdgcn_mfma_f32_16x16x32_bf16(a, b, c, 0, 0, 0)
// LDS-only barrier: does NOT drain vmcnt, so prefetched global loads stay in flight.
#define LDS_BARRIER() asm volatile("s_waitcnt lgkmcnt(0)\n\ts_barrier" ::: "memory")

static __device__ __forceinline__ u16 f2bf(float v) {
    __hip_bfloat16 h = __float2bfloat16(v);
    return *reinterpret_cast<u16*>(&h);
}

// ---------------- Kernel 1: LayerNorm + dual projection + mask ----------------
__global__ __launch_bounds__(256) void ln_proj_kernel(
    const float* __restrict__ m, const int* __restrict__ mask,
    const float* __restrict__ gamma, const float* __restrict__ beta,
    const float* __restrict__ Wa, const float* __restrict__ Wb,
    u16* __restrict__ a_out, u16* __restrict__ b_out)
{
    __shared__ float Wl[2][64][33];
    __shared__ float mn_s[64][65];
    __shared__ float mf_s[64];
    int n = blockIdx.x, tid = threadIdx.x;
    int wv = tid >> 6, lane = tid & 63;

    #pragma unroll
    for (int rep = 0; rep < 2; ++rep) {
        int p = rep * 1024 + tid * 4;
        int c = p >> 6, k0 = p & 63;
        float4 va = *(const float4*)(Wa + p);
        float4 vb = *(const float4*)(Wb + p);
        Wl[0][k0 + 0][c] = va.x; Wl[0][k0 + 1][c] = va.y;
        Wl[0][k0 + 2][c] = va.z; Wl[0][k0 + 3][c] = va.w;
        Wl[1][k0 + 0][c] = vb.x; Wl[1][k0 + 1][c] = vb.y;
        Wl[1][k0 + 2][c] = vb.z; Wl[1][k0 + 3][c] = vb.w;
    }

    float gl = gamma[lane], bl = beta[lane];
    for (int it = 0; it < 16; ++it) {
        int s = wv * 16 + it;
        float x = m[(s * NT + n) * 64 + lane];
        float v = x;
        #pragma unroll
        for (int off = 1; off < 64; off <<= 1) v += __shfl_xor(v, off);
        float mu = v * (1.0f / 64.0f);
        float d = x - mu;
        float v2 = d * d;
        #pragma unroll
        for (int off = 1; off < 64; off <<= 1) v2 += __shfl_xor(v2, off);
        float rstd = rsqrtf(v2 * (1.0f / 64.0f) + LN_EPS);
        mn_s[lane][s] = d * rstd * gl + bl;
    }
    if (tid < 64) mf_s[tid] = (float)mask[tid * NT + n];
    __syncthreads();

    int c = tid & 31, sg = tid >> 5;
    float accA[8], accB[8];
    #pragma unroll
    for (int j = 0; j < 8; ++j) { accA[j] = 0.f; accB[j] = 0.f; }
    for (int k = 0; k < 64; ++k) {
        float wa = Wl[0][k][c], wb = Wl[1][k][c];
        #pragma unroll
        for (int j = 0; j < 8; ++j) {
            float mnv = mn_s[k][sg * 8 + j];
            accA[j] += mnv * wa;
            accB[j] += mnv * wb;
        }
    }
    u16x8 pa, pb;
    #pragma unroll
    for (int j = 0; j < 8; ++j) {
        float mfv = mf_s[sg * 8 + j];
        pa[j] = f2bf(accA[j] * mfv);
        pb[j] = f2bf(accB[j] * mfv);
    }
    int off = n * (CH * SD) + c * SD + sg * 8;
    *(u16x8*)(a_out + off) = pa;
    *(u16x8*)(b_out + off) = pb;
}

// ---------------- Kernel 2: pairwise mask denom -> reciprocal ----------------
__global__ __launch_bounds__(384) void denom_kernel(const int* __restrict__ mask,
                                                    float* __restrict__ rdenom)
{
    int i = blockIdx.x, j = threadIdx.x;
    int acc = 0;
    #pragma unroll 8
    for (int s = 0; s < SD; ++s)
        acc += mask[s * NT + i] * mask[s * NT + j];
    rdenom[i * NT + j] = 1.0f / (float)max(acc, 1);
}

// ---------------- Kernel 3: Wo -> bf16 ----------------
__global__ __launch_bounds__(512) void wo_conv_kernel(const float* __restrict__ wo,
                                                      u16* __restrict__ wo_bf)
{
    int idx = blockIdx.x * 512 + threadIdx.x;
    if (idx < CO * 1024) wo_bf[idx] = f2bf(wo[idx]);
}

// ---------------- Kernel 4: fused OPM + down-projection, i-batched ----------------
// Block tile: 16 i x 8 j. Loop over 32 c-chunks; per chunk:
//   stage A: zc[i,j,d] = sum_s b[s,j,d]*a[s,i,c]  (bt frags register-resident)
//   stage B: acc[i,j,o] += zc @ wo[o][c*32..+32]  (persistent accumulators)
// zc double-buffered in LDS (8 KB each), rows of 64B with XOR-swizzled 16B chunks
// (chunk' = chunk ^ ((row>>1)&3)) -> 2-way max on both b64 writes and b128 reads.
// wo/a fragment loads software-pipelined 1-2 chunks ahead; barrier drains lgkm only.
__global__ __launch_bounds__(256, 2) void opm_kernel(
    const u16* __restrict__ a2,   // [384][32][64]  a[i][c][s]
    const u16* __restrict__ bt,   // [384][32][64]  b[j][d][s]
    const u16* __restrict__ wo,   // [128][1024]
    const float* __restrict__ rdenom,
    const float* __restrict__ bo,
    float* __restrict__ out)      // [384][384][128]
{
    __shared__ u16 zbuf[2][128 * 32];   // 2 x 8 KB

    int bid = blockIdx.x;
    int ig = bid / 48;            // 0..23  (16 i per group)
    int jb = bid % 48;            // 0..47  (8 j per group)
    int tid = threadIdx.x;
    int w = tid >> 6, lane = tid & 63;
    int l15 = lane & 15, quad = lane >> 4;
    int mh = w & 1, nh = w >> 1;

    // ---- persistent bt fragments (A-operand): wave w owns mtiles w*4..w*4+3 ----
    short8 btf[4][2];
    #pragma unroll
    for (int mt4 = 0; mt4 < 4; ++mt4) {
        int mt = w * 4 + mt4;
        int j = mt >> 1, d = (mt & 1) * 16 + l15;
        const u16* p = bt + ((jb * 8 + j) * CH + d) * SD + quad * 8;
        btf[mt4][0] = *(const short8*)(p);
        btf[mt4][1] = *(const short8*)(p + 32);
    }

    const u16* abase = a2 + (ig * 16 + l15) * (CH * SD) + quad * 8;  // + c*64 (+32)
    const u16* wbase = wo + (nh * 64 + l15) * 1024 + quad * 8;       // + ni*16*1024 + c*32

    int swz = (l15 >> 1) & 3;     // row-dependent chunk swizzle key

    // stage A: produce zc for chunk c into buf
    auto stageA = [&](short8 a0, short8 a1, u16* buf) {
        #pragma unroll
        for (int mt4 = 0; mt4 < 4; ++mt4) {
            f32x4 za = {0.f, 0.f, 0.f, 0.f};
            za = MFMA16(btf[mt4][0], a0, za);
            za = MFMA16(btf[mt4][1], a1, za);
            int mt = w * 4 + mt4;
            int j = mt >> 1;
            int m2 = j * 16 + l15;                       // row = j*16 + i
            int chunk = (((mt & 1) * 2 + (quad >> 1)) ^ swz);
            u16x4 pk;
            #pragma unroll
            for (int r = 0; r < 4; ++r) pk[r] = f2bf(za[r]);
            *(u16x4*)((char*)buf + m2 * 64 + chunk * 16 + (quad & 1) * 8) = pk;
        }
    };

    f32x4 acc[4][4];
    #pragma unroll
    for (int mi = 0; mi < 4; ++mi)
        #pragma unroll
        for (int ni = 0; ni < 4; ++ni)
            acc[mi][ni] = (f32x4){0.f, 0.f, 0.f, 0.f};

    // stage B: consume buf against wo frags (4 ntiles) into persistent acc
    auto stageB = [&](short8* wof, const u16* buf) {
        short8 zf[4];
        int chunk = quad ^ swz;
        #pragma unroll
        for (int mi = 0; mi < 4; ++mi) {
            int m2 = (mh * 4 + mi) * 16 + l15;
            zf[mi] = *(const short8*)((const char*)buf + m2 * 64 + chunk * 16);
        }
        #pragma unroll
        for (int mi = 0; mi < 4; ++mi)
            #pragma unroll
            for (int ni = 0; ni < 4; ++ni)
                acc[mi][ni] = MFMA16(zf[mi], wof[ni], acc[mi][ni]);
    };

    auto loadWof = [&](int c, short8* dst) {
        #pragma unroll
        for (int ni = 0; ni < 4; ++ni)
            dst[ni] = *(const short8*)(wbase + ni * 16 * 1024 + c * 32);
    };
    auto loadAf = [&](int c, short8* dst) {
        dst[0] = *(const short8*)(abase + c * 64);
        dst[1] = *(const short8*)(abase + c * 64 + 32);
    };

    // ---- pipeline prologue ----
    short8 wof[4], wof_n[4], afc[2], af_n[2], af_nn[2];
    loadAf(0, afc);
    stageA(afc[0], afc[1], zbuf[0]);
    loadWof(0, wof);
    loadAf(1, af_n);
    LDS_BARRIER();

    // ---- main loop over 32 c-chunks ----
    #pragma unroll 2
    for (int t = 0; t < 32; ++t) {
        int cn  = (t + 1 < 32) ? t + 1 : 31;
        int cnn = (t + 2 < 32) ? t + 2 : 31;
        loadWof(cn, wof_n);          // prefetch wo for t+1
        loadAf(cnn, af_nn);          // prefetch a for t+2
        stageB(wof, zbuf[t & 1]);
        if (t < 31) stageA(af_n[0], af_n[1], zbuf[(t + 1) & 1]);
        LDS_BARRIER();
        #pragma unroll
        for (int q = 0; q < 4; ++q) wof[q] = wof_n[q];
        af_n[0] = af_nn[0]; af_n[1] = af_nn[1];
    }

    // ---- epilogue: divide by denom, add bias, store ----
    float bov[4];
    #pragma unroll
    for (int ni = 0; ni < 4; ++ni) bov[ni] = bo[nh * 64 + ni * 16 + l15];
    #pragma unroll
    for (int mi = 0; mi < 4; ++mi) {
        int j_g = jb * 8 + mh * 4 + mi;
        #pragma unroll
        for (int r = 0; r < 4; ++r) {
            int i_g = ig * 16 + quad * 4 + r;
            float rd = rdenom[i_g * NT + j_g];
            float* orow = out + (i_g * NT + j_g) * CO + nh * 64 + l15;
            #pragma unroll
            for (int ni = 0; ni < 4; ++ni)
                orow[ni * 16] = acc[mi][ni][r] * rd + bov[ni];
        }
    }
}

// ---------------- launch ----------------
extern "C" void kernel_launch(void* const* d_in, const int* in_sizes, int n_in,
                              void* d_out, int out_size, void* d_ws, size_t ws_size,
                              hipStream_t stream) {
    const float* m     = (const float*)d_in[0];
    const int*   mask  = (const int*)d_in[1];
    const float* gamma = (const float*)d_in[2];
    const float* beta  = (const float*)d_in[3];
    const float* Wa    = (const float*)d_in[4];
    const float* Wb    = (const float*)d_in[5];
    const float* Wo    = (const float*)d_in[6];
    const float* bo    = (const float*)d_in[7];
    float* out = (float*)d_out;

    char* ws = (char*)d_ws;
    u16*   a2    = (u16*)(ws);
    u16*   btp   = (u16*)(ws + 1572864);
    u16*   wo_bf = (u16*)(ws + 3145728);
    float* rden  = (float*)(ws + 3407872);

    ln_proj_kernel<<<NT, 256, 0, stream>>>(m, mask, gamma, beta, Wa, Wb, a2, btp);
    wo_conv_kernel<<<(CO * 1024 + 511) / 512, 512, 0, stream>>>(Wo, wo_bf);
    denom_kernel<<<NT, NT, 0, stream>>>(mask, rden);
    opm_kernel<<<24 * 48, 256, 0, stream>>>(a2, btp, wo_bf, rden, bo, out);
}